// Round 1
// 670.483 us; speedup vs baseline: 1.0175x; 1.0175x over previous
//
#include <hip/hip_runtime.h>
#include <math.h>

#define Bdim 64
#define Sdim 2048
#define Hdim 1024

typedef float f4 __attribute__((ext_vector_type(4)));   // clang vector: valid for nontemporal builtins

// Kernel A: v[b,j] = sum_k hid[b,k] * W[k,j]; c[b] = sum_k hid[b,k] * bias[k].
// grid (4, B), block 256. Each block covers 256 j-columns (64 float4 groups),
// k-range split across the 4 waves (chain length 256 -> LDS-reduced).
// W f4 loads: 64 lanes x 16 B = 1 KiB contiguous per instruction.
__global__ __launch_bounds__(256)
void proj_v_kernel(const float* __restrict__ hid, const float* __restrict__ W,
                   const float* __restrict__ bias, float* __restrict__ v,
                   float* __restrict__ c)
{
    __shared__ float sh[Hdim];
    __shared__ f4    red[4][64];
    __shared__ float cr[4];

    const int b    = blockIdx.y;
    const int t    = threadIdx.x;
    const int w    = t >> 6;
    const int lane = t & 63;

    for (int i = t; i < Hdim; i += 256) sh[i] = hid[b * Hdim + i];
    __syncthreads();

    const f4* W4 = (const f4*)W;                  // W4[k*256 + j4]
    const int j4 = blockIdx.x * 64 + lane;        // float4 column group

    f4 a0 = {0.f, 0.f, 0.f, 0.f};
    f4 a1 = {0.f, 0.f, 0.f, 0.f};
    const int k0 = w * 256;
    #pragma unroll 4
    for (int k = k0; k < k0 + 256; k += 2) {
        const f4 w0 = W4[(size_t)k * 256 + j4];
        const f4 w1 = W4[(size_t)(k + 1) * 256 + j4];
        a0 += sh[k] * w0;
        a1 += sh[k + 1] * w1;
    }
    a0 += a1;
    red[w][lane] = a0;
    __syncthreads();

    if (w == 0) {
        const f4 r = red[0][lane] + red[1][lane] + red[2][lane] + red[3][lane];
        ((f4*)v)[b * 256 + j4] = r;
    }

    if (blockIdx.x == 0) {                        // c[b] once per batch row
        float pc = 0.f;
        for (int k = t; k < Hdim; k += 256) pc = fmaf(sh[k], bias[k], pc);
        for (int off = 32; off > 0; off >>= 1) pc += __shfl_down(pc, off, 64);
        if (lane == 0) cr[w] = pc;
        __syncthreads();
        if (t == 0) c[b] = cr[0] + cr[1] + cr[2] + cr[3];
    }
}

// Kernel B: energies[b,s] = enc[b,s,:] . v[b,:] + c[b]  -> staged in d_out.
// One wave per 8 consecutive s-rows. v2: accumulate ALL 8 rows first
// (32 nontemporal f4 loads in flight per wave, zero DS ops between them),
// then ONE batched cross-lane reduction:
//   stage A: butterfly off=1,2,4 on all 8 accs (ILP-8, depth 3)
//            -> every lane holds S(i, g) = row-i partial over its 8-lane subgroup g=lane>>3
//   remap:   r(lane) = S(lane&7, lane>>3)   (static cndmask chain, no runtime reg index)
//   stage B: butterfly off=8,16,32 on r (depth 3) -> r = total of row (lane&7)
//   write:   lanes 0..7 store rows 0..7 -> one coalesced 32B transaction.
// DS ops per 8 rows: 27 (was 48), serial DS depth per 32KB: 6 (was ~48).
__global__ __launch_bounds__(256)
void energy_kernel(const float* __restrict__ enc, const float* __restrict__ v,
                   const float* __restrict__ c, float* __restrict__ out)
{
    const int b      = blockIdx.y;
    const int lane   = threadIdx.x & 63;
    const int wave   = threadIdx.x >> 6;
    const int s_base = blockIdx.x * 32 + wave * 8;

    const f4* vrow = (const f4*)(v + b * Hdim);
    const f4 v0 = vrow[lane];
    const f4 v1 = vrow[lane + 64];
    const f4 v2 = vrow[lane + 128];
    const f4 v3 = vrow[lane + 192];
    const float cb = c[b];

    const f4* erow = (const f4*)(enc + ((size_t)b * Sdim + s_base) * Hdim);

    float acc[8];
    #pragma unroll
    for (int i = 0; i < 8; ++i) {
        const f4* ep = erow + (size_t)i * (Hdim / 4);
        const f4 a0 = __builtin_nontemporal_load(ep + lane);
        const f4 a1 = __builtin_nontemporal_load(ep + lane + 64);
        const f4 a2 = __builtin_nontemporal_load(ep + lane + 128);
        const f4 a3 = __builtin_nontemporal_load(ep + lane + 192);

        f4 p = a0 * v0;
        p += a1 * v1;
        p += a2 * v2;
        p += a3 * v3;
        acc[i] = (p.x + p.y) + (p.z + p.w);
    }

    // stage A: reduce within 8-lane subgroups, all 8 rows in parallel
    #pragma unroll
    for (int off = 1; off < 8; off <<= 1) {
        #pragma unroll
        for (int i = 0; i < 8; ++i)
            acc[i] += __shfl_xor(acc[i], off, 64);
    }

    // remap: lane supplies row (lane&7)'s partial for its subgroup (lane>>3)
    float r = acc[0];
    #pragma unroll
    for (int i = 1; i < 8; ++i)
        if ((lane & 7) == i) r = acc[i];

    // stage B: reduce across the 8 subgroups
    #pragma unroll
    for (int off = 8; off < 64; off <<= 1)
        r += __shfl_xor(r, off, 64);

    if (lane < 8)
        __builtin_nontemporal_store(r + cb, &out[b * Sdim + s_base + lane]);
}

// Kernel C: softmax over batch axis, in place on d_out (B x S).
// grid 32, block 256: block covers 64 s-columns; wave w holds b in [16w,16w+16).
// All loads/stores coalesced (lane = s); cross-wave max/sum via LDS.
__global__ __launch_bounds__(256)
void softmax_kernel(float* __restrict__ out)
{
    __shared__ float smax[4][64];
    __shared__ float ssum[4][64];
    const int t    = threadIdx.x;
    const int w    = t >> 6;
    const int lane = t & 63;
    const int s    = blockIdx.x * 64 + lane;

    float vals[16];
    float m = -1e30f;
    #pragma unroll
    for (int i = 0; i < 16; ++i) {
        vals[i] = out[(size_t)(w * 16 + i) * Sdim + s];
        m = fmaxf(m, vals[i]);
    }
    smax[w][lane] = m;
    __syncthreads();
    m = fmaxf(fmaxf(smax[0][lane], smax[1][lane]),
              fmaxf(smax[2][lane], smax[3][lane]));

    float sum = 0.f;
    #pragma unroll
    for (int i = 0; i < 16; ++i) { vals[i] = __expf(vals[i] - m); sum += vals[i]; }
    ssum[w][lane] = sum;
    __syncthreads();
    const float inv = 1.f / (ssum[0][lane] + ssum[1][lane] +
                             ssum[2][lane] + ssum[3][lane]);
    #pragma unroll
    for (int i = 0; i < 16; ++i)
        out[(size_t)(w * 16 + i) * Sdim + s] = vals[i] * inv;
}

extern "C" void kernel_launch(void* const* d_in, const int* in_sizes, int n_in,
                              void* d_out, int out_size, void* d_ws, size_t ws_size,
                              hipStream_t stream)
{
    const float* hid  = (const float*)d_in[0];   // (1, B, H)
    const float* enc  = (const float*)d_in[1];   // (B, S, H)
    const float* W    = (const float*)d_in[2];   // (H, H)  [out, in]
    const float* bias = (const float*)d_in[3];   // (H,)
    float* out = (float*)d_out;                  // (B, S)

    float* v = (float*)d_ws;                     // B*H floats = 256 KiB
    float* c = v + Bdim * Hdim;                  // B floats

    proj_v_kernel<<<dim3(4, Bdim), 256, 0, stream>>>(hid, W, bias, v, c);
    energy_kernel<<<dim3(Sdim / 32, Bdim), 256, 0, stream>>>(enc, v, c, out);
    softmax_kernel<<<dim3(Sdim / 64), 256, 0, stream>>>(out);
}